// Round 4
// baseline (105.748 us; speedup 1.0000x reference)
//
#include <hip/hip_runtime.h>

// CCN_2D on MI355X. N=256 vertices, K=16, C0=16, H=32.
// Facts (validated by exact passes):
//  * CH rows one-hot => T_t[a][b][c] = Fin[j_t, P_t[a], P_t[b], c].
//  * A = I_16 collapses contract18 to 6 effective weight matrices.
//  * P_t[t] = -1 (no self-loops) => c17 / d_ttt terms vanish.
//  * Layer-1 input is broadcast of X => rank-1 closed form, no gathers.
//  * F1 channel-interleaved: chunk (i*16+q)*128 + c4*16 + p holds channels
//    4c4..4c4+3 of F1[i][p][q][:].
// Window = 2x ~43.9us harness ws-poison fills (untouchable) + ~17us kernels.
// R1: SGPR-stream weights serialize on load latency (SGPR file too small).
// R3: v_pk_fma halved gather VALU; MM_DS = LDS-broadcast weights + pkfma.
// R4 (this round), all bit-exact:
//  * l1: Z4 is GROUP-uniform (fb depends on t only) and Z5 is BLOCK-uniform
//    (f5 = m^2) -> hoisted to a tiny coop phase; deletes 256 pkfma/thread.
//  * l2: sab shfl_xor butterfly == balanced add tree (fadd commutes) ->
//    computed from sRpp by the otherwise-IDLE half-B waves in the B3->B4
//    window; deletes 256 issues from half A's critical path.
//  * op_sel on v_pk_fma_f32 (pkfma_lo/pkfma_hi) consumes packed coefficient
//    halves directly: no splat movs; l1 5-matvec 10->5 VALU/c, l2 epilogue
//    matvec 12->6 VALU/c-pair. Each half is an IEEE fma -> exact.
//  * sRpp/s_stb strides 36->34 to fit s_sab under the 64 KB static-LDS cap.

constexpr int KN = 16, HH = 32, NV = 256, C2 = 32;

typedef float f32x2 __attribute__((ext_vector_type(2)));
typedef float f32x4 __attribute__((ext_vector_type(4)));

__device__ __forceinline__ f32x2 pkfma(f32x2 a, f32x2 b, f32x2 c) {
    f32x2 d;
    asm("v_pk_fma_f32 %0, %1, %2, %3" : "=v"(d) : "v"(a), "v"(b), "v"(c));
    return d;
}
// lo/hi-splat coefficient variants: both result halves use cf.lo (resp cf.hi).
__device__ __forceinline__ f32x2 pkfma_lo(f32x2 cf, f32x2 w, f32x2 acc) {
    f32x2 d;
    asm("v_pk_fma_f32 %0, %1, %2, %3 op_sel:[0,0,0] op_sel_hi:[0,1,1]"
        : "=v"(d) : "v"(cf), "v"(w), "v"(acc));
    return d;
}
__device__ __forceinline__ f32x2 pkfma_hi(f32x2 cf, f32x2 w, f32x2 acc) {
    f32x2 d;
    asm("v_pk_fma_f32 %0, %1, %2, %3 op_sel:[1,0,0] op_sel_hi:[1,1,1]"
        : "=v"(d) : "v"(cf), "v"(w), "v"(acc));
    return d;
}
__device__ __forceinline__ f32x2 pkadd(f32x2 a, f32x2 b) {
    f32x2 d;
    asm("v_pk_add_f32 %0, %1, %2" : "=v"(d) : "v"(a), "v"(b));
    return d;
}
__device__ __forceinline__ f32x2 pkmul(f32x2 a, f32x2 b) {
    f32x2 d;
    asm("v_pk_mul_f32 %0, %1, %2" : "=v"(d) : "v"(a), "v"(b));
    return d;
}
__device__ __forceinline__ f32x2 vlo(f32x4 v) { return __builtin_shufflevector(v, v, 0, 1); }
__device__ __forceinline__ f32x2 vhi(f32x4 v) { return __builtin_shufflevector(v, v, 2, 3); }

// ACC2[16] (f32x2, channel-pairs of 32 outputs) += cf_ci * W[ci][:] over
// ci in [0, 2*NC2). Coefficients given as packed pairs CPARR[cp] = (cf_{2cp},
// cf_{2cp+1}); op_sel consumes each half directly (no splat movs).
// Per-element accumulation order: ci ascending — identical to scalar chain.
#define MM_DSP(WLDS, NC2, CPARR, ACC2) do {                                    \
    const f32x4* W4_ = (const f32x4*)(WLDS);                                   \
    _Pragma("unroll")                                                          \
    for (int cp = 0; cp < (NC2); ++cp) {                                       \
        const f32x2 cfp_ = (CPARR)[cp];                                        \
        _Pragma("unroll")                                                      \
        for (int h4 = 0; h4 < 8; ++h4) {                                       \
            const f32x4 w_ = W4_[(2 * cp) * 8 + h4];                           \
            (ACC2)[2*h4+0] = pkfma_lo(cfp_, vlo(w_), (ACC2)[2*h4+0]);          \
            (ACC2)[2*h4+1] = pkfma_lo(cfp_, vhi(w_), (ACC2)[2*h4+1]);          \
        }                                                                      \
        _Pragma("unroll")                                                      \
        for (int h4 = 0; h4 < 8; ++h4) {                                       \
            const f32x4 w_ = W4_[(2 * cp + 1) * 8 + h4];                       \
            (ACC2)[2*h4+0] = pkfma_hi(cfp_, vlo(w_), (ACC2)[2*h4+0]);          \
            (ACC2)[2*h4+1] = pkfma_hi(cfp_, vhi(w_), (ACC2)[2*h4+1]);          \
        }                                                                      \
    }                                                                          \
} while (0)

// ---------------- layer 1 ----------------
// E1 slices (512 floats each): 0:Wsb 1:Wab 2:W16 3:Wt2(verbatim) 4:Wtb 5:Wal
// pre = vy*(m*Y0.Wsb) + (m^2*Y0).Wab + vy*(Y0.W16) + (16Z2).Wt2v + Z4.Wtb
//       + dxy*Z5.Wal   (x16 folded into the coefficient: pow2, exact)
// Output layout (float4 chunks): F1c chunk index = (i*16+q)*128 + c4*16 + p,
// holding channels c4*4..c4*4+3 of logical F1[i][p][q][:]. (q,p) = (y,x).
__global__ __launch_bounds__(512)
void ccn_l1(const float* __restrict__ X, const int* __restrict__ nbrs,
            const float* __restrict__ W1, const float* __restrict__ bias,
            float* __restrict__ F1c, float* __restrict__ outz,
            const float* __restrict__ W2f, float* __restrict__ Wsb2)
{
    __shared__ float sE1[6 * 512];       // 12 KB
    __shared__ float sPP2[8 * 256 * 4];  // 32 KB, channel-major [h4][cell][4]
    __shared__ float sX[16][20];
    __shared__ float sV[16][164];        // 5 matvec results x 32 per group
    __shared__ float s_Z4[16][20];       // group-uniform Z4, coop-computed
    __shared__ float s_Z5[16];           // block-uniform Z5
    __shared__ int   s_nbi[16];
    __shared__ int   s_nbj[16][17];
    __shared__ int   s_P[16][16];
    __shared__ int   s_vm[16];
    __shared__ float s_m[16];

    const int tid  = threadIdx.x;
    const int i    = ((blockIdx.x & 7) << 5) | (blockIdx.x >> 3);  // XCD swizzle

    if (blockIdx.x == 0 && tid == 0) outz[0] = 0.f;   // zero accumulator for l2

    // blocks 0,1: precompute the combined layer-2 slice Wsb2 into ws.
    if (blockIdx.x < 2) {
        const int u = (blockIdx.x << 9) | tid;
        float acc = 0.f;
        #pragma unroll
        for (int g = 6; g < 15; ++g) acc += W2f[g * 1024 + u];
        Wsb2[u] = 16.f * W2f[u] + W2f[5 * 1024 + u] + 16.f * acc;
    }

    if (tid < 16) s_nbi[tid] = nbrs[i * 16 + tid];
    __syncthreads();  // B0

    if (tid < 256) {
        const int t = tid >> 4, y = tid & 15;
        const int j = s_nbi[t];
        s_nbj[t][y] = nbrs[j * 16 + y];
        sX[t][y]    = X[j * 16 + y];
    } else {
        const int u = tid - 256;       // E1 entries 0..255
        float acc = 0.f;
        #pragma unroll
        for (int g = 6; g < 15; ++g) acc += W1[g * 512 + u];
        sE1[u]        = 16.f * W1[u] + W1[5 * 512 + u] + 16.f * acc;
        sE1[512 + u]  = W1[512 + u];
        sE1[1024 + u] = W1[15 * 512 + u];
        sE1[1536 + u] = W1[2 * 512 + u];
        sE1[2048 + u] = W1[3 * 512 + u];
        sE1[2560 + u] = W1[4 * 512 + u];
    }
    __syncthreads();  // B1

    if (tid < 256) {
        const int t = tid >> 4, y = tid & 15;
        const int tgt = s_nbi[y];
        int p = -1;
        #pragma unroll
        for (int q = 0; q < 16; ++q) if (s_nbj[t][q] == tgt) p = q;
        s_P[t][y] = p;
        unsigned long long bal = __ballot(p >= 0);
        if (y == 0) {
            int vm = (int)((bal >> ((t & 3) * 16)) & 0xFFFFull);
            s_vm[t] = vm;
            s_m[t]  = (float)__popc(vm);
        }
    } else {
        const int u = tid;             // E1 entries 256..511
        float acc = 0.f;
        #pragma unroll
        for (int g = 6; g < 15; ++g) acc += W1[g * 512 + u];
        sE1[u]        = 16.f * W1[u] + W1[5 * 512 + u] + 16.f * acc;
        sE1[512 + u]  = W1[512 + u];
        sE1[1024 + u] = W1[15 * 512 + u];
        sE1[1536 + u] = W1[2 * 512 + u];
        sE1[2048 + u] = W1[3 * 512 + u];
        sE1[2560 + u] = W1[4 * 512 + u];
    }
    __syncthreads();  // B2

    // ---- coop Z phase: Z4[t][c] (was computed 16x redundantly) and
    //      Z5[c] (was 256x redundant). Same fmaf chains => bit-exact.
    if (tid < 256) {
        const int t = tid >> 4, c = tid & 15;
        float acc = 0.f;
        #pragma unroll
        for (int tp = 0; tp < 16; ++tp) {
            const float fb = ((s_vm[tp] >> t) & 1) ? s_m[tp] : 0.f;
            acc = fmaf(fb, sX[tp][c], acc);
        }
        s_Z4[t][c] = acc;
    } else if (tid < 272) {
        const int c = tid - 256;
        float acc = 0.f;
        #pragma unroll
        for (int tp = 0; tp < 16; ++tp) {
            const float mt = s_m[tp];
            acc = fmaf(mt * mt, sX[tp][c], acc);
        }
        s_Z5[c] = acc;
    }
    __syncthreads();  // B2.5

    if (tid < 256) {
        // ---- half A: 5 cooperative matvecs (lane y -> h=2y,2y+1),
        //      c-pair loop with op_sel coefficient halves ----
        const int t = tid >> 4, y = tid & 15;
        f32x2 Y0p[8];
        #pragma unroll
        for (int c4 = 0; c4 < 4; ++c4) {
            const f32x4 v = *(const f32x4*)&sX[t][4 * c4];
            Y0p[2*c4+0] = vlo(v); Y0p[2*c4+1] = vhi(v);
        }
        const float m = s_m[t];
        const f32x2 mp2 = {m, m};
        f32x2 v0p = {0.f,0.f}, v1p = {0.f,0.f}, v2p = {0.f,0.f};
        f32x2 v3p = {0.f,0.f}, v4p = {0.f,0.f};
        const float2* Wsb = (const float2*)(sE1 + 0 * 512);
        const float2* Wab = (const float2*)(sE1 + 1 * 512);
        const float2* W16 = (const float2*)(sE1 + 2 * 512);
        const float2* Wtb = (const float2*)(sE1 + 4 * 512);
        const float2* Wal = (const float2*)(sE1 + 5 * 512);
        #pragma unroll
        for (int cp = 0; cp < 8; ++cp) {
            const f32x2 cf0p = pkmul(mp2, Y0p[cp]);     // m*Y0[c] per half
            const f32x2 cf1p = pkmul(mp2, cf0p);        // m*cf0
            const f32x2 cf2p = Y0p[cp];
            const f32x2 cf3p = *(const f32x2*)&s_Z4[t][2 * cp];
            const f32x2 cf4p = *(const f32x2*)&s_Z5[2 * cp];
            const int i0 = (2 * cp) * 16 + y, i1 = (2 * cp + 1) * 16 + y;
            f32x2 w;
            w = *(const f32x2*)&Wsb[i0]; v0p = pkfma_lo(cf0p, w, v0p);
            w = *(const f32x2*)&Wsb[i1]; v0p = pkfma_hi(cf0p, w, v0p);
            w = *(const f32x2*)&Wab[i0]; v1p = pkfma_lo(cf1p, w, v1p);
            w = *(const f32x2*)&Wab[i1]; v1p = pkfma_hi(cf1p, w, v1p);
            w = *(const f32x2*)&W16[i0]; v2p = pkfma_lo(cf2p, w, v2p);
            w = *(const f32x2*)&W16[i1]; v2p = pkfma_hi(cf2p, w, v2p);
            w = *(const f32x2*)&Wtb[i0]; v3p = pkfma_lo(cf3p, w, v3p);
            w = *(const f32x2*)&Wtb[i1]; v3p = pkfma_hi(cf3p, w, v3p);
            w = *(const f32x2*)&Wal[i0]; v4p = pkfma_lo(cf4p, w, v4p);
            w = *(const f32x2*)&Wal[i1]; v4p = pkfma_hi(cf4p, w, v4p);
        }
        *(f32x2*)&sV[t][0 * 32 + 2 * y] = v0p;
        *(f32x2*)&sV[t][1 * 32 + 2 * y] = v1p;
        *(f32x2*)&sV[t][2 * 32 + 2 * y] = v2p;
        *(f32x2*)&sV[t][3 * 32 + 2 * y] = v3p;
        *(f32x2*)&sV[t][4 * 32 + 2 * y] = v4p;
    } else {
        // ---- half B: Z2 (packed) + Wt2 MM_DSP, park channel-major ----
        const int w = tid - 256;
        const int t = w >> 4, y = w & 15, x = t;
        f32x2 Z22[8];
        #pragma unroll
        for (int c = 0; c < 8; ++c) Z22[c] = (f32x2){0.f,0.f};
        #pragma unroll
        for (int tp = 0; tp < 16; ++tp) {
            const int vm = s_vm[tp];
            const float f2 = (float)((vm >> x) & (vm >> y) & 1);
            const f32x2 f22 = {f2, f2};
            #pragma unroll
            for (int c4 = 0; c4 < 4; ++c4) {
                const f32x4 v = *(const f32x4*)&sX[tp][4 * c4];
                Z22[2*c4+0] = pkfma(f22, vlo(v), Z22[2*c4+0]);
                Z22[2*c4+1] = pkfma(f22, vhi(v), Z22[2*c4+1]);
            }
        }
        // Wt2 = 16*W1[2*512+..] (slot 3 verbatim); pre-scale pairs (exact).
        f32x2 Z22s[8];
        const f32x2 sixteen = {16.f, 16.f};
        #pragma unroll
        for (int k = 0; k < 8; ++k) Z22s[k] = pkmul(sixteen, Z22[k]);
        f32x2 pp2[16];
        #pragma unroll
        for (int h = 0; h < 16; ++h) pp2[h] = (f32x2){0.f,0.f};
        MM_DSP(sE1 + 3 * 512, 8, Z22s, pp2);
        // park: cell keyed as (y*16 + t) so reader (q,p) hits (q*16+p).
        const int cell = y * 16 + t;
        #pragma unroll
        for (int h4 = 0; h4 < 8; ++h4) {
            const int base = (h4 * 256 + cell) * 4;
            *(f32x2*)&sPP2[base]     = pp2[2*h4+0];
            *(f32x2*)&sPP2[base + 2] = pp2[2*h4+1];
        }
    }
    __syncthreads();  // B3 (sV + sPP2 + s_P ready) — final barrier

    if (tid < 256) {
        // output thread (q,p) computes cell (x=p, y=q), stores coalesced.
        const int q = tid >> 4, p = tid & 15;
        const float vy  = (s_P[p][q] >= 0) ? 1.f : 0.f;
        const float dxy = (p == q) ? 1.f : 0.f;
        const f32x2 vy2 = {vy, vy}, dxy2 = {dxy, dxy};
        float4* F4 = (float4*)F1c;
        const size_t basec = ((size_t)i * 16 + q) * 128 + p;
        #pragma unroll
        for (int h4 = 0; h4 < 8; ++h4) {
            const f32x4 V0 = *(const f32x4*)&sV[p][0 * 32 + 4 * h4];
            const f32x4 V1 = *(const f32x4*)&sV[p][1 * 32 + 4 * h4];
            const f32x4 V2 = *(const f32x4*)&sV[p][2 * 32 + 4 * h4];
            const f32x4 V3 = *(const f32x4*)&sV[p][3 * 32 + 4 * h4];
            const f32x4 V4 = *(const f32x4*)&sV[p][4 * 32 + 4 * h4];
            const f32x4 PP = *(const f32x4*)&sPP2[(h4 * 256 + q * 16 + p) * 4];
            const f32x2 blo = *(const f32x2*)&bias[4 * h4];
            const f32x2 bhi = *(const f32x2*)&bias[4 * h4 + 2];
            // order per element: vy*(V0+V2) + V1 + V3 + dxy*V4 + PP + bias
            f32x2 slo = pkadd(vlo(V0), vlo(V2));
            slo = pkfma(vy2, slo, vlo(V1));
            slo = pkadd(slo, vlo(V3));
            slo = pkfma(dxy2, vlo(V4), slo);
            slo = pkadd(slo, vlo(PP));
            slo = pkadd(slo, blo);
            f32x2 shi = pkadd(vhi(V0), vhi(V2));
            shi = pkfma(vy2, shi, vhi(V1));
            shi = pkadd(shi, vhi(V3));
            shi = pkfma(dxy2, vhi(V4), shi);
            shi = pkadd(shi, vhi(PP));
            shi = pkadd(shi, bhi);
            F4[basec + h4 * 16] = make_float4(fmaxf(slo.x, 0.f), fmaxf(slo.y, 0.f),
                                              fmaxf(shi.x, 0.f), fmaxf(shi.y, 0.f));
        }
    }
}

// ---------------- layer 2 ----------------
// MM slices in LDS (verbatim vectorized copies, no prep):
//   sMM[0]:Wsb2 (from ws)  sMM[1]:W16=W2+15*1024  sMM[2]:Wt2=W2+2*1024
//   sW3[0]:Wab=W2+1024  sW3[1]:Wtb=W2+3*1024  sW3[2]:Wal=W2+4*1024
// F1c chunk (j*16+q)*128 + c4*16 + p = channels 4c4..4c4+3 of F1[j][p][q][:].
// sRpp stride 34 (2-bank stagger); s_stb/s_sab stride 34.
__global__ __launch_bounds__(512)
void ccn_l2(const float* __restrict__ F1c, const int* __restrict__ nbrs,
            const float* __restrict__ W2, const float* __restrict__ bias,
            const float* __restrict__ fcw, const float* __restrict__ fcb,
            float* __restrict__ out, const float* __restrict__ Wsb2)
{
    __shared__ float sMM[3 * 1024];    // 12 KB: MM weights (uniform ds reads)
    __shared__ float sW3[3 * 1024];    // 12 KB: epilogue matvec weights
    __shared__ float sRpp[256 * 34];   // 34 KB: R rows, then half-B pp results
    __shared__ float s_stb[16 * 34];
    __shared__ float s_sab[16 * 34];   // per-t row sums (replaces shfl_xor)
    __shared__ float s_sall[C2];
    __shared__ int   s_nbi[16];
    __shared__ int   s_PQ[16 * 17];    // nbj, then overwritten with P (wave-local)
    __shared__ float s_red[4];

    const int tid  = threadIdx.x;
    const int i    = ((blockIdx.x & 7) << 5) | (blockIdx.x >> 3);  // XCD swizzle
    const int lane = tid & 63;
    const f32x4* F4 = (const f32x4*)F1c;

    if (tid < 16) s_nbi[tid] = nbrs[i * 16 + tid];
    __syncthreads();  // B0

    if (tid < 256) {
        const int t = tid >> 4, y = tid & 15;
        const int j = s_nbi[t];
        s_PQ[t * 17 + y] = nbrs[j * 16 + y];
    } else {
        const int w = tid - 256;
        ((f32x4*)sMM)[w]       = ((const f32x4*)Wsb2)[w];
        ((f32x4*)sMM)[256 + w] = ((const f32x4*)(W2 + 15 * 1024))[w];
        ((f32x4*)sMM)[512 + w] = ((const f32x4*)(W2 +  2 * 1024))[w];
        ((f32x4*)sW3)[w]       = ((const f32x4*)(W2 +  1 * 1024))[w];
        ((f32x4*)sW3)[256 + w] = ((const f32x4*)(W2 +  3 * 1024))[w];
        ((f32x4*)sW3)[512 + w] = ((const f32x4*)(W2 +  4 * 1024))[w];
    }
    __syncthreads();  // B1

    if (tid < 256) {
        const int t = tid >> 4, y = tid & 15;
        const int tgt = s_nbi[y];
        int p = -1;
        #pragma unroll
        for (int q = 0; q < 16; ++q) if (s_PQ[t * 17 + q] == tgt) p = q;
        s_PQ[t * 17 + y] = p;   // overwrite: reads above precede write (wave lockstep)
    }
    __syncthreads();  // B2

    f32x2 pre2[16];
    f32x2 pp2[16];

    if (tid < 256) {
        // ---- half A: R gather (packed) + Wsb/W16 MM_DSP ----
        const int t = tid >> 4, y = tid & 15;
        const int j = s_nbi[t];
        const int p = s_PQ[t * 17 + y];
        const float mp = (p >= 0) ? 1.f : 0.f;
        const int pc = p >= 0 ? p : 0;
        const size_t jbase = (size_t)j * 2048;   // 16*128 chunks per tile

        f32x2 R2[16];
        #pragma unroll
        for (int c = 0; c < 16; ++c) R2[c] = (f32x2){0.f, 0.f};
        #pragma unroll
        for (int b = 0; b < 16; ++b) {
            const int q = s_PQ[t * 17 + b];
            const float mm = (q >= 0) ? mp : 0.f;
            const f32x2 mm2 = {mm, mm};
            const int qc = q >= 0 ? q : 0;
            const size_t rb = jbase + (size_t)qc * 128 + pc;
            #pragma unroll
            for (int c4 = 0; c4 < 8; ++c4) {
                const f32x4 v = F4[rb + c4 * 16];
                R2[2*c4+0] = pkfma(mm2, vlo(v), R2[2*c4+0]);
                R2[2*c4+1] = pkfma(mm2, vhi(v), R2[2*c4+1]);
            }
        }
        {
            float* dst = &sRpp[(t * 16 + y) * 34];
            #pragma unroll
            for (int c4 = 0; c4 < 8; ++c4) {
                *(f32x2*)&dst[4*c4]     = R2[2*c4+0];
                *(f32x2*)&dst[4*c4 + 2] = R2[2*c4+1];
            }
        }

        #pragma unroll
        for (int h = 0; h < 16; ++h) pre2[h] = (f32x2){0.f, 0.f};
        MM_DSP(sMM, 16, R2, pre2);                 // Wsb^T R

        f32x2 D2[16];
        {
            const f32x2 mp2 = {mp, mp};
            const size_t db = jbase + (size_t)pc * 128 + pc;
            #pragma unroll
            for (int c4 = 0; c4 < 8; ++c4) {
                const f32x4 v = F4[db + c4 * 16];
                D2[2*c4+0] = pkmul(mp2, vlo(v));
                D2[2*c4+1] = pkmul(mp2, vhi(v));
            }
        }
        MM_DSP(sMM + 1024, 16, D2, pre2);          // W16^T D
    } else {
        // ---- half B: ST gather (packed) + Wt2 MM_DSP ----
        const int w = tid - 256;
        const int g = w >> 4, l = w & 15;              // output (x=l, y=g)
        f32x2 ST2[16];
        #pragma unroll
        for (int c = 0; c < 16; ++c) ST2[c] = (f32x2){0.f, 0.f};
        #pragma unroll
        for (int tp = 0; tp < 16; ++tp) {
            const int jt = s_nbi[tp];
            const int py = s_PQ[tp * 17 + g];          // group-uniform
            const int px = s_PQ[tp * 17 + l];          // lane-varying
            const float mm = (px >= 0 && py >= 0) ? 1.f : 0.f;
            const f32x2 mm2 = {mm, mm};
            const int pyc = py >= 0 ? py : 0;
            const int pxc = px >= 0 ? px : 0;
            const size_t rb = (size_t)jt * 2048 + (size_t)pyc * 128 + pxc;
            #pragma unroll
            for (int c4 = 0; c4 < 8; ++c4) {
                const f32x4 v = F4[rb + c4 * 16];
                ST2[2*c4+0] = pkfma(mm2, vlo(v), ST2[2*c4+0]);
                ST2[2*c4+1] = pkfma(mm2, vhi(v), ST2[2*c4+1]);
            }
        }
        // Wt2 = 16*(W2+2*1024); pre-scale pairs (pow2, exact).
        f32x2 ST2s[16];
        const f32x2 sixteen = {16.f, 16.f};
        #pragma unroll
        for (int k = 0; k < 16; ++k) ST2s[k] = pkmul(sixteen, ST2[k]);
        #pragma unroll
        for (int h = 0; h < 16; ++h) pp2[h] = (f32x2){0.f, 0.f};
        MM_DSP(sMM + 2048, 16, ST2s, pp2);         // Wt2^T ST
    }
    __syncthreads();  // B3  (sR rows complete)

    if (tid < 256) {
        // stb[x2][c] = sum_t R[t][x2][c]  (ascending-t fadd chain, as before)
        #pragma unroll
        for (int k = 0; k < 2; ++k) {
            const int x2 = (tid >> 5) + 8 * k;
            const int c = tid & 31;
            float s = 0.f;
            #pragma unroll
            for (int tt = 0; tt < 16; ++tt) s += sRpp[(tt * 16 + x2) * 34 + c];
            s_stb[x2 * 34 + c] = s;
        }
    } else {
        // half B (idle window): sab_t[c-pair] = balanced-tree sum over y of
        // R[(t,y)][c] — bit-identical to the old shfl_xor butterfly.
        const int w = tid - 256;
        const int t = w >> 4, cp = w & 15;
        f32x2 v[16];
        #pragma unroll
        for (int yy = 0; yy < 16; ++yy)
            v[yy] = *(const f32x2*)&sRpp[(t * 16 + yy) * 34 + 2 * cp];
        f32x2 t1[8], t2[4], t3[2];
        #pragma unroll
        for (int k = 0; k < 8; ++k) t1[k] = pkadd(v[2*k], v[2*k+1]);
        #pragma unroll
        for (int k = 0; k < 4; ++k) t2[k] = pkadd(t1[2*k], t1[2*k+1]);
        #pragma unroll
        for (int k = 0; k < 2; ++k) t3[k] = pkadd(t2[2*k], t2[2*k+1]);
        *(f32x2*)&s_sab[t * 34 + 2 * cp] = pkadd(t3[0], t3[1]);
    }
    __syncthreads();  // B4  (stb + sab complete; sR now dead)

    if (tid < 256) {
        if (tid < 32) {
            float s = 0.f;
            #pragma unroll
            for (int x2 = 0; x2 < 16; ++x2) s += s_stb[x2 * 34 + tid];
            s_sall[tid] = s;
        }
    } else {
        // half B parks its pp into the dead sR buffer at row x*16+y = l*16+g
        const int w = tid - 256;
        const int g = w >> 4, l = w & 15;
        float* dst = &sRpp[(l * 16 + g) * 34];
        #pragma unroll
        for (int h4 = 0; h4 < 8; ++h4) {
            *(f32x2*)&dst[4*h4]     = pp2[2*h4+0];
            *(f32x2*)&dst[4*h4 + 2] = pp2[2*h4+1];
        }
    }
    __syncthreads();  // B5

    if (tid < 256) {
        const int t = tid >> 4, y = tid & 15, x = t;
        const float dxy = (x == y) ? 1.f : 0.f;
        // cooperative matvecs Wab/Wtb/Wal (lane y -> h=2y,2y+1), c-pair loop
        // with op_sel halves; per-element order +Wab_c,+Wtb_c,c ascending.
        f32x2 Sp = {0.f, 0.f}, Lp = {0.f, 0.f};
        {
            const float2* Wab = (const float2*)(sW3 + 0 * 1024);
            const float2* Wtb = (const float2*)(sW3 + 1 * 1024);
            const float2* Wal = (const float2*)(sW3 + 2 * 1024);
            #pragma unroll
            for (int cp = 0; cp < 16; ++cp) {
                const f32x2 cfap = *(const f32x2*)&s_sab[t * 34 + 2 * cp];
                const f32x2 cftp = *(const f32x2*)&s_stb[t * 34 + 2 * cp];
                const f32x2 cflp = *(const f32x2*)&s_sall[2 * cp];
                const int i0 = (2 * cp) * 16 + y, i1 = (2 * cp + 1) * 16 + y;
                f32x2 w;
                w = *(const f32x2*)&Wab[i0]; Sp = pkfma_lo(cfap, w, Sp);
                w = *(const f32x2*)&Wtb[i0]; Sp = pkfma_lo(cftp, w, Sp);
                w = *(const f32x2*)&Wab[i1]; Sp = pkfma_hi(cfap, w, Sp);
                w = *(const f32x2*)&Wtb[i1]; Sp = pkfma_hi(cftp, w, Sp);
                w = *(const f32x2*)&Wal[i0]; Lp = pkfma_lo(cflp, w, Lp);
                w = *(const f32x2*)&Wal[i1]; Lp = pkfma_hi(cflp, w, Lp);
            }
        }
        const float S0 = Sp.x, S1 = Sp.y, L0 = Lp.x, L1 = Lp.y;
        const int gbase = (t & 3) * 16;
        #pragma unroll
        for (int h = 0; h < HH; ++h) {
            const int src = gbase + (h >> 1);
            const float sv = (h & 1) ? S1 : S0;
            const float lv = (h & 1) ? L1 : L0;
            pre2[h >> 1][h & 1] += __shfl(sv, src, 64) + dxy * __shfl(lv, src, 64);
        }
        // pick up half B's Wt2 contribution (row t*16+y)
        {
            const float* ppr = &sRpp[(t * 16 + y) * 34];
            #pragma unroll
            for (int h4 = 0; h4 < 8; ++h4) {
                const f32x2 a = *(const f32x2*)&ppr[4*h4];
                const f32x2 b = *(const f32x2*)&ppr[4*h4 + 2];
                pre2[2*h4+0] = pkadd(pre2[2*h4+0], a);
                pre2[2*h4+1] = pkadd(pre2[2*h4+1], b);
            }
        }
        // epilogue: bias, relu, dot fcw, wave reduce
        float local = 0.f;
        #pragma unroll
        for (int h = 0; h < HH; ++h) {
            float v = pre2[h >> 1][h & 1] + bias[h];
            v = v > 0.f ? v : 0.f;
            local += v * fcw[h];
        }
        #pragma unroll
        for (int off = 32; off > 0; off >>= 1) local += __shfl_down(local, off, 64);
        if (lane == 0) s_red[tid >> 6] = local;
    }
    __syncthreads();  // B6
    if (tid == 0) {
        const float v = s_red[0] + s_red[1] + s_red[2] + s_red[3]
                      + fcb[0] * (1.f / 256.f);
        atomicAdd(out, v);
    }
}

extern "C" void kernel_launch(void* const* d_in, const int* in_sizes, int n_in,
                              void* d_out, int out_size, void* d_ws, size_t ws_size,
                              hipStream_t stream) {
    const float* X    = (const float*)d_in[0];
    const int*   nbrs = (const int*)  d_in[1];
    const float* W1   = (const float*)d_in[2];
    const float* b1   = (const float*)d_in[3];
    const float* W2   = (const float*)d_in[4];
    const float* b2   = (const float*)d_in[5];
    const float* fc_w = (const float*)d_in[6];
    const float* fc_b = (const float*)d_in[7];
    float* outp = (float*)d_out;

    float* F1c  = (float*)d_ws;          // 256*16*16*32 floats = 8 MB
    float* Wsb2 = F1c + 2097152;         // 1024 floats, written by l1 blocks 0,1

    ccn_l1<<<NV, 512, 0, stream>>>(X, nbrs, W1, b1, F1c, outp, W2, Wsb2);
    ccn_l2<<<NV, 512, 0, stream>>>(F1c, nbrs, W2, b2, fc_w, fc_b, outp, Wsb2);
}

// Round 5
// 103.235 us; speedup vs baseline: 1.0243x; 1.0243x over previous
//
#include <hip/hip_runtime.h>

// CCN_2D on MI355X. N=256 vertices, K=16, C0=16, H=32.
// Facts (validated by exact passes):
//  * CH rows one-hot => T_t[a][b][c] = Fin[j_t, P_t[a], P_t[b], c].
//  * A = I_16 collapses contract18 to 6 effective weight matrices.
//  * P_t[t] = -1 (no self-loops) => c17 / d_ttt terms vanish.
//  * Layer-1 input is broadcast of X => rank-1 closed form, no gathers.
//  * F1 channel-interleaved: chunk (i*16+q)*128 + c4*16 + p holds channels
//    4c4..4c4+3 of F1[i][p][q][:].
// Window = 2x ~43.5us harness ws-poison fills (untouchable, and they impose
// +-1.5us run-to-run variance) + ~18us kernels+gaps.
// R1: SGPR-stream weights serialize on load latency. R3: v_pk_fma packing.
// R4: Z4/Z5 hoist, sab LDS tree, op_sel coefficient halves (all ~neutral:
// kernels no longer issue-bound at that granularity).
// R5 (this round): l2 is L2-BW-bound (~1.05 MB/block gather ~= 7.3us at
// ~144 GB/s/CU). ~30% of R-gather rows and ~53% of ST-gather cells are
// masked-dead (mm==0) but still LOADED (clamped row 0) and accumulated as
// +0. Skip them with validity branches — BIT-EXACT because accumulators
// and F1 values are never -0/negative (ReLU outputs), so acc+(+0)==acc and
// fmaf(1,v,acc)==fadd(v,acc). Predicted l2 VMEM -35%.

constexpr int KN = 16, HH = 32, NV = 256, C2 = 32;

typedef float f32x2 __attribute__((ext_vector_type(2)));
typedef float f32x4 __attribute__((ext_vector_type(4)));

__device__ __forceinline__ f32x2 pkfma(f32x2 a, f32x2 b, f32x2 c) {
    f32x2 d;
    asm("v_pk_fma_f32 %0, %1, %2, %3" : "=v"(d) : "v"(a), "v"(b), "v"(c));
    return d;
}
// lo/hi-splat coefficient variants: both result halves use cf.lo (resp cf.hi).
__device__ __forceinline__ f32x2 pkfma_lo(f32x2 cf, f32x2 w, f32x2 acc) {
    f32x2 d;
    asm("v_pk_fma_f32 %0, %1, %2, %3 op_sel:[0,0,0] op_sel_hi:[0,1,1]"
        : "=v"(d) : "v"(cf), "v"(w), "v"(acc));
    return d;
}
__device__ __forceinline__ f32x2 pkfma_hi(f32x2 cf, f32x2 w, f32x2 acc) {
    f32x2 d;
    asm("v_pk_fma_f32 %0, %1, %2, %3 op_sel:[1,0,0] op_sel_hi:[1,1,1]"
        : "=v"(d) : "v"(cf), "v"(w), "v"(acc));
    return d;
}
__device__ __forceinline__ f32x2 pkadd(f32x2 a, f32x2 b) {
    f32x2 d;
    asm("v_pk_add_f32 %0, %1, %2" : "=v"(d) : "v"(a), "v"(b));
    return d;
}
__device__ __forceinline__ f32x2 pkmul(f32x2 a, f32x2 b) {
    f32x2 d;
    asm("v_pk_mul_f32 %0, %1, %2" : "=v"(d) : "v"(a), "v"(b));
    return d;
}
__device__ __forceinline__ f32x2 vlo(f32x4 v) { return __builtin_shufflevector(v, v, 0, 1); }
__device__ __forceinline__ f32x2 vhi(f32x4 v) { return __builtin_shufflevector(v, v, 2, 3); }

// ACC2[16] (f32x2, channel-pairs of 32 outputs) += cf_ci * W[ci][:] over
// ci in [0, 2*NC2). Coefficients given as packed pairs CPARR[cp]; op_sel
// consumes each half directly. Per-element order: ci ascending.
#define MM_DSP(WLDS, NC2, CPARR, ACC2) do {                                    \
    const f32x4* W4_ = (const f32x4*)(WLDS);                                   \
    _Pragma("unroll")                                                          \
    for (int cp = 0; cp < (NC2); ++cp) {                                       \
        const f32x2 cfp_ = (CPARR)[cp];                                        \
        _Pragma("unroll")                                                      \
        for (int h4 = 0; h4 < 8; ++h4) {                                       \
            const f32x4 w_ = W4_[(2 * cp) * 8 + h4];                           \
            (ACC2)[2*h4+0] = pkfma_lo(cfp_, vlo(w_), (ACC2)[2*h4+0]);          \
            (ACC2)[2*h4+1] = pkfma_lo(cfp_, vhi(w_), (ACC2)[2*h4+1]);          \
        }                                                                      \
        _Pragma("unroll")                                                      \
        for (int h4 = 0; h4 < 8; ++h4) {                                       \
            const f32x4 w_ = W4_[(2 * cp + 1) * 8 + h4];                       \
            (ACC2)[2*h4+0] = pkfma_hi(cfp_, vlo(w_), (ACC2)[2*h4+0]);          \
            (ACC2)[2*h4+1] = pkfma_hi(cfp_, vhi(w_), (ACC2)[2*h4+1]);          \
        }                                                                      \
    }                                                                          \
} while (0)

// ---------------- layer 1 ----------------
// E1 slices (512 floats each): 0:Wsb 1:Wab 2:W16 3:Wt2(verbatim) 4:Wtb 5:Wal
// pre = vy*(m*Y0.Wsb) + (m^2*Y0).Wab + vy*(Y0.W16) + (16Z2).Wt2v + Z4.Wtb
//       + dxy*Z5.Wal   (x16 folded into the coefficient: pow2, exact)
// Output layout (float4 chunks): F1c chunk index = (i*16+q)*128 + c4*16 + p,
// holding channels c4*4..c4*4+3 of logical F1[i][p][q][:]. (q,p) = (y,x).
__global__ __launch_bounds__(512)
void ccn_l1(const float* __restrict__ X, const int* __restrict__ nbrs,
            const float* __restrict__ W1, const float* __restrict__ bias,
            float* __restrict__ F1c, float* __restrict__ outz,
            const float* __restrict__ W2f, float* __restrict__ Wsb2)
{
    __shared__ float sE1[6 * 512];       // 12 KB
    __shared__ float sPP2[8 * 256 * 4];  // 32 KB, channel-major [h4][cell][4]
    __shared__ float sX[16][20];
    __shared__ float sV[16][164];        // 5 matvec results x 32 per group
    __shared__ float s_Z4[16][20];       // group-uniform Z4, coop-computed
    __shared__ float s_Z5[16];           // block-uniform Z5
    __shared__ int   s_nbi[16];
    __shared__ int   s_nbj[16][17];
    __shared__ int   s_P[16][16];
    __shared__ int   s_vm[16];
    __shared__ float s_m[16];

    const int tid  = threadIdx.x;
    const int i    = ((blockIdx.x & 7) << 5) | (blockIdx.x >> 3);  // XCD swizzle

    if (blockIdx.x == 0 && tid == 0) outz[0] = 0.f;   // zero accumulator for l2

    // blocks 0,1: precompute the combined layer-2 slice Wsb2 into ws.
    if (blockIdx.x < 2) {
        const int u = (blockIdx.x << 9) | tid;
        float acc = 0.f;
        #pragma unroll
        for (int g = 6; g < 15; ++g) acc += W2f[g * 1024 + u];
        Wsb2[u] = 16.f * W2f[u] + W2f[5 * 1024 + u] + 16.f * acc;
    }

    if (tid < 16) s_nbi[tid] = nbrs[i * 16 + tid];
    __syncthreads();  // B0

    if (tid < 256) {
        const int t = tid >> 4, y = tid & 15;
        const int j = s_nbi[t];
        s_nbj[t][y] = nbrs[j * 16 + y];
        sX[t][y]    = X[j * 16 + y];
    } else {
        const int u = tid - 256;       // E1 entries 0..255
        float acc = 0.f;
        #pragma unroll
        for (int g = 6; g < 15; ++g) acc += W1[g * 512 + u];
        sE1[u]        = 16.f * W1[u] + W1[5 * 512 + u] + 16.f * acc;
        sE1[512 + u]  = W1[512 + u];
        sE1[1024 + u] = W1[15 * 512 + u];
        sE1[1536 + u] = W1[2 * 512 + u];
        sE1[2048 + u] = W1[3 * 512 + u];
        sE1[2560 + u] = W1[4 * 512 + u];
    }
    __syncthreads();  // B1

    if (tid < 256) {
        const int t = tid >> 4, y = tid & 15;
        const int tgt = s_nbi[y];
        int p = -1;
        #pragma unroll
        for (int q = 0; q < 16; ++q) if (s_nbj[t][q] == tgt) p = q;
        s_P[t][y] = p;
        unsigned long long bal = __ballot(p >= 0);
        if (y == 0) {
            int vm = (int)((bal >> ((t & 3) * 16)) & 0xFFFFull);
            s_vm[t] = vm;
            s_m[t]  = (float)__popc(vm);
        }
    } else {
        const int u = tid;             // E1 entries 256..511
        float acc = 0.f;
        #pragma unroll
        for (int g = 6; g < 15; ++g) acc += W1[g * 512 + u];
        sE1[u]        = 16.f * W1[u] + W1[5 * 512 + u] + 16.f * acc;
        sE1[512 + u]  = W1[512 + u];
        sE1[1024 + u] = W1[15 * 512 + u];
        sE1[1536 + u] = W1[2 * 512 + u];
        sE1[2048 + u] = W1[3 * 512 + u];
        sE1[2560 + u] = W1[4 * 512 + u];
    }
    __syncthreads();  // B2

    // ---- coop Z phase: Z4[t][c] (was computed 16x redundantly) and
    //      Z5[c] (was 256x redundant). Same fmaf chains => bit-exact.
    if (tid < 256) {
        const int t = tid >> 4, c = tid & 15;
        float acc = 0.f;
        #pragma unroll
        for (int tp = 0; tp < 16; ++tp) {
            const float fb = ((s_vm[tp] >> t) & 1) ? s_m[tp] : 0.f;
            acc = fmaf(fb, sX[tp][c], acc);
        }
        s_Z4[t][c] = acc;
    } else if (tid < 272) {
        const int c = tid - 256;
        float acc = 0.f;
        #pragma unroll
        for (int tp = 0; tp < 16; ++tp) {
            const float mt = s_m[tp];
            acc = fmaf(mt * mt, sX[tp][c], acc);
        }
        s_Z5[c] = acc;
    }
    __syncthreads();  // B2.5

    if (tid < 256) {
        // ---- half A: 5 cooperative matvecs (lane y -> h=2y,2y+1),
        //      c-pair loop with op_sel coefficient halves ----
        const int t = tid >> 4, y = tid & 15;
        f32x2 Y0p[8];
        #pragma unroll
        for (int c4 = 0; c4 < 4; ++c4) {
            const f32x4 v = *(const f32x4*)&sX[t][4 * c4];
            Y0p[2*c4+0] = vlo(v); Y0p[2*c4+1] = vhi(v);
        }
        const float m = s_m[t];
        const f32x2 mp2 = {m, m};
        f32x2 v0p = {0.f,0.f}, v1p = {0.f,0.f}, v2p = {0.f,0.f};
        f32x2 v3p = {0.f,0.f}, v4p = {0.f,0.f};
        const float2* Wsb = (const float2*)(sE1 + 0 * 512);
        const float2* Wab = (const float2*)(sE1 + 1 * 512);
        const float2* W16 = (const float2*)(sE1 + 2 * 512);
        const float2* Wtb = (const float2*)(sE1 + 4 * 512);
        const float2* Wal = (const float2*)(sE1 + 5 * 512);
        #pragma unroll
        for (int cp = 0; cp < 8; ++cp) {
            const f32x2 cf0p = pkmul(mp2, Y0p[cp]);     // m*Y0[c] per half
            const f32x2 cf1p = pkmul(mp2, cf0p);        // m*cf0
            const f32x2 cf2p = Y0p[cp];
            const f32x2 cf3p = *(const f32x2*)&s_Z4[t][2 * cp];
            const f32x2 cf4p = *(const f32x2*)&s_Z5[2 * cp];
            const int i0 = (2 * cp) * 16 + y, i1 = (2 * cp + 1) * 16 + y;
            f32x2 w;
            w = *(const f32x2*)&Wsb[i0]; v0p = pkfma_lo(cf0p, w, v0p);
            w = *(const f32x2*)&Wsb[i1]; v0p = pkfma_hi(cf0p, w, v0p);
            w = *(const f32x2*)&Wab[i0]; v1p = pkfma_lo(cf1p, w, v1p);
            w = *(const f32x2*)&Wab[i1]; v1p = pkfma_hi(cf1p, w, v1p);
            w = *(const f32x2*)&W16[i0]; v2p = pkfma_lo(cf2p, w, v2p);
            w = *(const f32x2*)&W16[i1]; v2p = pkfma_hi(cf2p, w, v2p);
            w = *(const f32x2*)&Wtb[i0]; v3p = pkfma_lo(cf3p, w, v3p);
            w = *(const f32x2*)&Wtb[i1]; v3p = pkfma_hi(cf3p, w, v3p);
            w = *(const f32x2*)&Wal[i0]; v4p = pkfma_lo(cf4p, w, v4p);
            w = *(const f32x2*)&Wal[i1]; v4p = pkfma_hi(cf4p, w, v4p);
        }
        *(f32x2*)&sV[t][0 * 32 + 2 * y] = v0p;
        *(f32x2*)&sV[t][1 * 32 + 2 * y] = v1p;
        *(f32x2*)&sV[t][2 * 32 + 2 * y] = v2p;
        *(f32x2*)&sV[t][3 * 32 + 2 * y] = v3p;
        *(f32x2*)&sV[t][4 * 32 + 2 * y] = v4p;
    } else {
        // ---- half B: Z2 (packed) + Wt2 MM_DSP, park channel-major ----
        const int w = tid - 256;
        const int t = w >> 4, y = w & 15, x = t;
        f32x2 Z22[8];
        #pragma unroll
        for (int c = 0; c < 8; ++c) Z22[c] = (f32x2){0.f,0.f};
        #pragma unroll
        for (int tp = 0; tp < 16; ++tp) {
            const int vm = s_vm[tp];
            const float f2 = (float)((vm >> x) & (vm >> y) & 1);
            const f32x2 f22 = {f2, f2};
            #pragma unroll
            for (int c4 = 0; c4 < 4; ++c4) {
                const f32x4 v = *(const f32x4*)&sX[tp][4 * c4];
                Z22[2*c4+0] = pkfma(f22, vlo(v), Z22[2*c4+0]);
                Z22[2*c4+1] = pkfma(f22, vhi(v), Z22[2*c4+1]);
            }
        }
        // Wt2 = 16*W1[2*512+..] (slot 3 verbatim); pre-scale pairs (exact).
        f32x2 Z22s[8];
        const f32x2 sixteen = {16.f, 16.f};
        #pragma unroll
        for (int k = 0; k < 8; ++k) Z22s[k] = pkmul(sixteen, Z22[k]);
        f32x2 pp2[16];
        #pragma unroll
        for (int h = 0; h < 16; ++h) pp2[h] = (f32x2){0.f,0.f};
        MM_DSP(sE1 + 3 * 512, 8, Z22s, pp2);
        // park: cell keyed as (y*16 + t) so reader (q,p) hits (q*16+p).
        const int cell = y * 16 + t;
        #pragma unroll
        for (int h4 = 0; h4 < 8; ++h4) {
            const int base = (h4 * 256 + cell) * 4;
            *(f32x2*)&sPP2[base]     = pp2[2*h4+0];
            *(f32x2*)&sPP2[base + 2] = pp2[2*h4+1];
        }
    }
    __syncthreads();  // B3 (sV + sPP2 + s_P ready) — final barrier

    if (tid < 256) {
        // output thread (q,p) computes cell (x=p, y=q), stores coalesced.
        const int q = tid >> 4, p = tid & 15;
        const float vy  = (s_P[p][q] >= 0) ? 1.f : 0.f;
        const float dxy = (p == q) ? 1.f : 0.f;
        const f32x2 vy2 = {vy, vy}, dxy2 = {dxy, dxy};
        float4* F4 = (float4*)F1c;
        const size_t basec = ((size_t)i * 16 + q) * 128 + p;
        #pragma unroll
        for (int h4 = 0; h4 < 8; ++h4) {
            const f32x4 V0 = *(const f32x4*)&sV[p][0 * 32 + 4 * h4];
            const f32x4 V1 = *(const f32x4*)&sV[p][1 * 32 + 4 * h4];
            const f32x4 V2 = *(const f32x4*)&sV[p][2 * 32 + 4 * h4];
            const f32x4 V3 = *(const f32x4*)&sV[p][3 * 32 + 4 * h4];
            const f32x4 V4 = *(const f32x4*)&sV[p][4 * 32 + 4 * h4];
            const f32x4 PP = *(const f32x4*)&sPP2[(h4 * 256 + q * 16 + p) * 4];
            const f32x2 blo = *(const f32x2*)&bias[4 * h4];
            const f32x2 bhi = *(const f32x2*)&bias[4 * h4 + 2];
            // order per element: vy*(V0+V2) + V1 + V3 + dxy*V4 + PP + bias
            f32x2 slo = pkadd(vlo(V0), vlo(V2));
            slo = pkfma(vy2, slo, vlo(V1));
            slo = pkadd(slo, vlo(V3));
            slo = pkfma(dxy2, vlo(V4), slo);
            slo = pkadd(slo, vlo(PP));
            slo = pkadd(slo, blo);
            f32x2 shi = pkadd(vhi(V0), vhi(V2));
            shi = pkfma(vy2, shi, vhi(V1));
            shi = pkadd(shi, vhi(V3));
            shi = pkfma(dxy2, vhi(V4), shi);
            shi = pkadd(shi, vhi(PP));
            shi = pkadd(shi, bhi);
            F4[basec + h4 * 16] = make_float4(fmaxf(slo.x, 0.f), fmaxf(slo.y, 0.f),
                                              fmaxf(shi.x, 0.f), fmaxf(shi.y, 0.f));
        }
    }
}

// ---------------- layer 2 ----------------
// MM slices in LDS (verbatim vectorized copies, no prep):
//   sMM[0]:Wsb2 (from ws)  sMM[1]:W16=W2+15*1024  sMM[2]:Wt2=W2+2*1024
//   sW3[0]:Wab=W2+1024  sW3[1]:Wtb=W2+3*1024  sW3[2]:Wal=W2+4*1024
// F1c chunk (j*16+q)*128 + c4*16 + p = channels 4c4..4c4+3 of F1[j][p][q][:].
// Gathers gated on mask validity (R5): dead rows/cells are SKIPPED, not
// loaded-and-zeroed. Bit-exact: acc and F1 are never -0 (ReLU outputs),
// so acc+(+0)==acc, and fmaf(1,v,acc)==v+acc.
__global__ __launch_bounds__(512)
void ccn_l2(const float* __restrict__ F1c, const int* __restrict__ nbrs,
            const float* __restrict__ W2, const float* __restrict__ bias,
            const float* __restrict__ fcw, const float* __restrict__ fcb,
            float* __restrict__ out, const float* __restrict__ Wsb2)
{
    __shared__ float sMM[3 * 1024];    // 12 KB: MM weights (uniform ds reads)
    __shared__ float sW3[3 * 1024];    // 12 KB: epilogue matvec weights
    __shared__ float sRpp[256 * 34];   // 34 KB: R rows, then half-B pp results
    __shared__ float s_stb[16 * 34];
    __shared__ float s_sab[16 * 34];   // per-t row sums (LDS balanced tree)
    __shared__ float s_sall[C2];
    __shared__ int   s_nbi[16];
    __shared__ int   s_PQ[16 * 17];    // nbj, then overwritten with P (wave-local)
    __shared__ float s_red[4];

    const int tid  = threadIdx.x;
    const int i    = ((blockIdx.x & 7) << 5) | (blockIdx.x >> 3);  // XCD swizzle
    const int lane = tid & 63;
    const f32x4* F4 = (const f32x4*)F1c;

    if (tid < 16) s_nbi[tid] = nbrs[i * 16 + tid];
    __syncthreads();  // B0

    if (tid < 256) {
        const int t = tid >> 4, y = tid & 15;
        const int j = s_nbi[t];
        s_PQ[t * 17 + y] = nbrs[j * 16 + y];
    } else {
        const int w = tid - 256;
        ((f32x4*)sMM)[w]       = ((const f32x4*)Wsb2)[w];
        ((f32x4*)sMM)[256 + w] = ((const f32x4*)(W2 + 15 * 1024))[w];
        ((f32x4*)sMM)[512 + w] = ((const f32x4*)(W2 +  2 * 1024))[w];
        ((f32x4*)sW3)[w]       = ((const f32x4*)(W2 +  1 * 1024))[w];
        ((f32x4*)sW3)[256 + w] = ((const f32x4*)(W2 +  3 * 1024))[w];
        ((f32x4*)sW3)[512 + w] = ((const f32x4*)(W2 +  4 * 1024))[w];
    }
    __syncthreads();  // B1

    if (tid < 256) {
        const int t = tid >> 4, y = tid & 15;
        const int tgt = s_nbi[y];
        int p = -1;
        #pragma unroll
        for (int q = 0; q < 16; ++q) if (s_PQ[t * 17 + q] == tgt) p = q;
        s_PQ[t * 17 + y] = p;   // overwrite: reads above precede write (wave lockstep)
    }
    __syncthreads();  // B2

    f32x2 pre2[16];
    f32x2 pp2[16];

    if (tid < 256) {
        // ---- half A: gated R gather + Wsb/W16 MM_DSP ----
        const int t = tid >> 4, y = tid & 15;
        const int j = s_nbi[t];
        const int p = s_PQ[t * 17 + y];
        const size_t jbase = (size_t)j * 2048;   // 16*128 chunks per tile

        f32x2 R2[16];
        #pragma unroll
        for (int c = 0; c < 16; ++c) R2[c] = (f32x2){0.f, 0.f};
        if (p >= 0) {
            #pragma unroll
            for (int b = 0; b < 16; ++b) {
                const int q = s_PQ[t * 17 + b];
                if (q >= 0) {
                    const size_t rb = jbase + (size_t)q * 128 + p;
                    #pragma unroll
                    for (int c4 = 0; c4 < 8; ++c4) {
                        const f32x4 v = F4[rb + c4 * 16];
                        R2[2*c4+0] = pkadd(vlo(v), R2[2*c4+0]);
                        R2[2*c4+1] = pkadd(vhi(v), R2[2*c4+1]);
                    }
                }
            }
        }
        {
            float* dst = &sRpp[(t * 16 + y) * 34];
            #pragma unroll
            for (int c4 = 0; c4 < 8; ++c4) {
                *(f32x2*)&dst[4*c4]     = R2[2*c4+0];
                *(f32x2*)&dst[4*c4 + 2] = R2[2*c4+1];
            }
        }

        #pragma unroll
        for (int h = 0; h < 16; ++h) pre2[h] = (f32x2){0.f, 0.f};
        MM_DSP(sMM, 16, R2, pre2);                 // Wsb^T R

        f32x2 D2[16];
        #pragma unroll
        for (int c = 0; c < 16; ++c) D2[c] = (f32x2){0.f, 0.f};
        if (p >= 0) {
            const size_t db = jbase + (size_t)p * 128 + p;
            #pragma unroll
            for (int c4 = 0; c4 < 8; ++c4) {
                const f32x4 v = F4[db + c4 * 16];
                D2[2*c4+0] = vlo(v);
                D2[2*c4+1] = vhi(v);
            }
        }
        MM_DSP(sMM + 1024, 16, D2, pre2);          // W16^T D
    } else {
        // ---- half B: gated ST gather + Wt2 MM_DSP ----
        const int w = tid - 256;
        const int g = w >> 4, l = w & 15;              // output (x=l, y=g)
        f32x2 ST2[16];
        #pragma unroll
        for (int c = 0; c < 16; ++c) ST2[c] = (f32x2){0.f, 0.f};
        #pragma unroll
        for (int tp = 0; tp < 16; ++tp) {
            const int py = s_PQ[tp * 17 + g];          // group-uniform
            const int px = s_PQ[tp * 17 + l];          // lane-varying
            if (py >= 0 && px >= 0) {
                const int jt = s_nbi[tp];
                const size_t rb = (size_t)jt * 2048 + (size_t)py * 128 + px;
                #pragma unroll
                for (int c4 = 0; c4 < 8; ++c4) {
                    const f32x4 v = F4[rb + c4 * 16];
                    ST2[2*c4+0] = pkadd(vlo(v), ST2[2*c4+0]);
                    ST2[2*c4+1] = pkadd(vhi(v), ST2[2*c4+1]);
                }
            }
        }
        // Wt2 = 16*(W2+2*1024); pre-scale pairs (pow2, exact).
        f32x2 ST2s[16];
        const f32x2 sixteen = {16.f, 16.f};
        #pragma unroll
        for (int k = 0; k < 16; ++k) ST2s[k] = pkmul(sixteen, ST2[k]);
        #pragma unroll
        for (int h = 0; h < 16; ++h) pp2[h] = (f32x2){0.f, 0.f};
        MM_DSP(sMM + 2048, 16, ST2s, pp2);         // Wt2^T ST
    }
    __syncthreads();  // B3  (sR rows complete)

    if (tid < 256) {
        // stb[x2][c] = sum_t R[t][x2][c]  (ascending-t fadd chain, as before)
        #pragma unroll
        for (int k = 0; k < 2; ++k) {
            const int x2 = (tid >> 5) + 8 * k;
            const int c = tid & 31;
            float s = 0.f;
            #pragma unroll
            for (int tt = 0; tt < 16; ++tt) s += sRpp[(tt * 16 + x2) * 34 + c];
            s_stb[x2 * 34 + c] = s;
        }
    } else {
        // half B (idle window): sab_t[c-pair] = balanced-tree sum over y of
        // R[(t,y)][c] — bit-identical to the old shfl_xor butterfly.
        const int w = tid - 256;
        const int t = w >> 4, cp = w & 15;
        f32x2 v[16];
        #pragma unroll
        for (int yy = 0; yy < 16; ++yy)
            v[yy] = *(const f32x2*)&sRpp[(t * 16 + yy) * 34 + 2 * cp];
        f32x2 t1[8], t2[4], t3[2];
        #pragma unroll
        for (int k = 0; k < 8; ++k) t1[k] = pkadd(v[2*k], v[2*k+1]);
        #pragma unroll
        for (int k = 0; k < 4; ++k) t2[k] = pkadd(t1[2*k], t1[2*k+1]);
        #pragma unroll
        for (int k = 0; k < 2; ++k) t3[k] = pkadd(t2[2*k], t2[2*k+1]);
        *(f32x2*)&s_sab[t * 34 + 2 * cp] = pkadd(t3[0], t3[1]);
    }
    __syncthreads();  // B4  (stb + sab complete; sR now dead)

    if (tid < 256) {
        if (tid < 32) {
            float s = 0.f;
            #pragma unroll
            for (int x2 = 0; x2 < 16; ++x2) s += s_stb[x2 * 34 + tid];
            s_sall[tid] = s;
        }
    } else {
        // half B parks its pp into the dead sR buffer at row x*16+y = l*16+g
        const int w = tid - 256;
        const int g = w >> 4, l = w & 15;
        float* dst = &sRpp[(l * 16 + g) * 34];
        #pragma unroll
        for (int h4 = 0; h4 < 8; ++h4) {
            *(f32x2*)&dst[4*h4]     = pp2[2*h4+0];
            *(f32x2*)&dst[4*h4 + 2] = pp2[2*h4+1];
        }
    }
    __syncthreads();  // B5

    if (tid < 256) {
        const int t = tid >> 4, y = tid & 15, x = t;
        const float dxy = (x == y) ? 1.f : 0.f;
        // cooperative matvecs Wab/Wtb/Wal (lane y -> h=2y,2y+1), c-pair loop
        // with op_sel halves; per-element order +Wab_c,+Wtb_c,c ascending.
        f32x2 Sp = {0.f, 0.f}, Lp = {0.f, 0.f};
        {
            const float2* Wab = (const float2*)(sW3 + 0 * 1024);
            const float2* Wtb = (const float2*)(sW3 + 1 * 1024);
            const float2* Wal = (const float2*)(sW3 + 2 * 1024);
            #pragma unroll
            for (int cp = 0; cp < 16; ++cp) {
                const f32x2 cfap = *(const f32x2*)&s_sab[t * 34 + 2 * cp];
                const f32x2 cftp = *(const f32x2*)&s_stb[t * 34 + 2 * cp];
                const f32x2 cflp = *(const f32x2*)&s_sall[2 * cp];
                const int i0 = (2 * cp) * 16 + y, i1 = (2 * cp + 1) * 16 + y;
                f32x2 w;
                w = *(const f32x2*)&Wab[i0]; Sp = pkfma_lo(cfap, w, Sp);
                w = *(const f32x2*)&Wtb[i0]; Sp = pkfma_lo(cftp, w, Sp);
                w = *(const f32x2*)&Wab[i1]; Sp = pkfma_hi(cfap, w, Sp);
                w = *(const f32x2*)&Wtb[i1]; Sp = pkfma_hi(cftp, w, Sp);
                w = *(const f32x2*)&Wal[i0]; Lp = pkfma_lo(cflp, w, Lp);
                w = *(const f32x2*)&Wal[i1]; Lp = pkfma_hi(cflp, w, Lp);
            }
        }
        const float S0 = Sp.x, S1 = Sp.y, L0 = Lp.x, L1 = Lp.y;
        const int gbase = (t & 3) * 16;
        #pragma unroll
        for (int h = 0; h < HH; ++h) {
            const int src = gbase + (h >> 1);
            const float sv = (h & 1) ? S1 : S0;
            const float lv = (h & 1) ? L1 : L0;
            pre2[h >> 1][h & 1] += __shfl(sv, src, 64) + dxy * __shfl(lv, src, 64);
        }
        // pick up half B's Wt2 contribution (row t*16+y)
        {
            const float* ppr = &sRpp[(t * 16 + y) * 34];
            #pragma unroll
            for (int h4 = 0; h4 < 8; ++h4) {
                const f32x2 a = *(const f32x2*)&ppr[4*h4];
                const f32x2 b = *(const f32x2*)&ppr[4*h4 + 2];
                pre2[2*h4+0] = pkadd(pre2[2*h4+0], a);
                pre2[2*h4+1] = pkadd(pre2[2*h4+1], b);
            }
        }
        // epilogue: bias, relu, dot fcw, wave reduce
        float local = 0.f;
        #pragma unroll
        for (int h = 0; h < HH; ++h) {
            float v = pre2[h >> 1][h & 1] + bias[h];
            v = v > 0.f ? v : 0.f;
            local += v * fcw[h];
        }
        #pragma unroll
        for (int off = 32; off > 0; off >>= 1) local += __shfl_down(local, off, 64);
        if (lane == 0) s_red[tid >> 6] = local;
    }
    __syncthreads();  // B6
    if (tid == 0) {
        const float v = s_red[0] + s_red[1] + s_red[2] + s_red[3]
                      + fcb[0] * (1.f / 256.f);
        atomicAdd(out, v);
    }
}

extern "C" void kernel_launch(void* const* d_in, const int* in_sizes, int n_in,
                              void* d_out, int out_size, void* d_ws, size_t ws_size,
                              hipStream_t stream) {
    const float* X    = (const float*)d_in[0];
    const int*   nbrs = (const int*)  d_in[1];
    const float* W1   = (const float*)d_in[2];
    const float* b1   = (const float*)d_in[3];
    const float* W2   = (const float*)d_in[4];
    const float* b2   = (const float*)d_in[5];
    const float* fc_w = (const float*)d_in[6];
    const float* fc_b = (const float*)d_in[7];
    float* outp = (float*)d_out;

    float* F1c  = (float*)d_ws;          // 256*16*16*32 floats = 8 MB
    float* Wsb2 = F1c + 2097152;         // 1024 floats, written by l1 blocks 0,1

    ccn_l1<<<NV, 512, 0, stream>>>(X, nbrs, W1, b1, F1c, outp, W2, Wsb2);
    ccn_l2<<<NV, 512, 0, stream>>>(F1c, nbrs, W2, b2, fc_w, fc_b, outp, Wsb2);
}